// Round 3
// baseline (192.741 us; speedup 1.0000x reference)
//
#include <hip/hip_runtime.h>
#include <hip/hip_cooperative_groups.h>
#include <math.h>

namespace cg = cooperative_groups;

// B=16, C=128, N=1024, HEADS=4, DIM_HEAD=32. qkv rows = 384.
#define CIN 128
#define NTOK 1024
#define SCALE_Q 0.17677669529663687f /* 32^-0.5 */
#define GN_EPS 1e-5f
#define PB (CIN * NTOK) /* 131072 */

// ---- workspace layout (float units), all plain stores (no init needed) ----
// wqkvb  bf16 [384][128]        @0      (24576 fl)
// pstats f32 [16][16][2]        @24576
// pqsum  f32 [16][16][128]      @25088
// W2b    bf16 [16][128][128]    @57856  (131072 fl)
// pM     f32 [16][16][4][32][32]@188928 (1048576 fl)
#define WS_WQKVB 0
#define WS_PSTATS 24576
#define WS_PQSUM 25088
#define WS_W2B 57856
#define WS_PM 188928

typedef __bf16 bf16x8 __attribute__((ext_vector_type(8)));
typedef float f32x4 __attribute__((ext_vector_type(4)));

__device__ __forceinline__ unsigned short f2bf(float f) {
    union { float f; unsigned u; } v; v.f = f;
    unsigned r = v.u + 0x7fffu + ((v.u >> 16) & 1u);
    return (unsigned short)(r >> 16);
}
__device__ __forceinline__ unsigned pack2(float a, float b) {
    return (unsigned)f2bf(a) | ((unsigned)f2bf(b) << 16);
}

// LDS map (bytes), one block = one (batch b, 64-token tile nt):
//  A: [0,17408)      Al  bf16 [64][136]  x-hat tile (persists P2..P4)
//  B: [17408,52224)  Xl f32[128][68] -> Bq/Bk/Bv/W2 bf16[128][136] -> kTl bf16[128][72] -> Ml f32[32][36]
//  C: [52224,70656)  qTl bf16 [128][72] -> Vl bf16 [64][136]
//  D: [70656,71680)  f32 scratch [256]
__global__ __launch_bounds__(256, 1) void k_fused(
    const float* __restrict__ x, const float* __restrict__ gw,
    const float* __restrict__ gb, const float* __restrict__ wqkv,
    const float* __restrict__ wout, const float* __restrict__ bout,
    float* __restrict__ y, float* __restrict__ ws) {
    __shared__ __align__(16) char smem[71680];
    unsigned short (*Al)[136] = (unsigned short(*)[136])smem;
    float (*Xl)[68] = (float(*)[68])(smem + 17408);
    unsigned short (*Bl)[136] = (unsigned short(*)[136])(smem + 17408);
    unsigned short (*kTl)[72] = (unsigned short(*)[72])(smem + 17408);
    float (*Ml)[36] = (float(*)[36])(smem + 17408);
    unsigned short (*qTl)[72] = (unsigned short(*)[72])(smem + 52224);
    unsigned short (*Vl)[136] = (unsigned short(*)[136])(smem + 52224);
    float* sD = (float*)(smem + 70656);

    unsigned short* wqkvb = (unsigned short*)(ws + WS_WQKVB);
    float* pstats = ws + WS_PSTATS;
    float* pqsum = ws + WS_PQSUM;
    unsigned short* W2b = (unsigned short*)(ws + WS_W2B);
    float* pM = ws + WS_PM;

    cg::grid_group grid = cg::this_grid();
    int bid = blockIdx.x, t = threadIdx.x;
    int b = bid >> 4, nt = bid & 15;
    int lane = t & 63, wave = t >> 6;
    int l15 = lane & 15, lk = (lane >> 4) * 8;
    int wn0 = (wave & 1) * 32, wo0 = (wave >> 1) * 64;

    // ================= P1: stats partials + wqkv -> bf16 =================
    {
        const float4* p = (const float4*)(x + (size_t)bid * 8192);
        float s = 0.f, s2 = 0.f;
        #pragma unroll
        for (int i = 0; i < 8; i++) {
            float4 v = p[t + 256 * i];
            s += v.x + v.y + v.z + v.w;
            s2 += v.x * v.x + v.y * v.y + v.z * v.z + v.w * v.w;
        }
        #pragma unroll
        for (int off = 32; off; off >>= 1) {
            s += __shfl_down(s, off);
            s2 += __shfl_down(s2, off);
        }
        if (lane == 0) { sD[wave * 2] = s; sD[wave * 2 + 1] = s2; }
        if (bid < 48) {
            float4 v = ((const float4*)(wqkv + bid * 1024))[t];
            uint2 pk2; pk2.x = pack2(v.x, v.y); pk2.y = pack2(v.z, v.w);
            *(uint2*)(wqkvb + bid * 1024 + t * 4) = pk2;
        }
        __syncthreads();
        if (t == 0) {
            pstats[bid * 2] = sD[0] + sD[2] + sD[4] + sD[6];
            pstats[bid * 2 + 1] = sD[1] + sD[3] + sD[5] + sD[7];
        }
    }
    grid.sync();

    // ================= P2: GN -> Al ; q,k MFMA ; softmax pieces ; M partial ==
    if (t < 32) sD[t] = pstats[b * 32 + t];
    __syncthreads();
    float mu, rsv;
    {
        float s = 0.f, s2 = 0.f;
        #pragma unroll
        for (int i = 0; i < 16; i++) { s += sD[2 * i]; s2 += sD[2 * i + 1]; }
        mu = s * (1.f / PB);
        float var = s2 * (1.f / PB) - mu * mu;
        rsv = rsqrtf(var + GN_EPS);
    }
    {   // stage x rows with GN applied
        int c = t >> 1, hf = t & 1;
        float g = gw[c] * rsv, bb = gb[c] - mu * g;
        const float4* src = (const float4*)(x + ((size_t)b * CIN + c) * NTOK + nt * 64 + hf * 32);
        #pragma unroll
        for (int i = 0; i < 8; i++) {
            float4 v = src[i];
            float4 r = { v.x * g + bb, v.y * g + bb, v.z * g + bb, v.w * g + bb };
            *(float4*)&Xl[c][hf * 32 + i * 4] = r;
        }
    }
    __syncthreads();
    {   // transpose + bf16 pack -> Al[n][c]
        int n = t & 63, kq = (t >> 6) * 32;
        unsigned pk[16];
        #pragma unroll
        for (int j = 0; j < 16; j++) pk[j] = pack2(Xl[kq + 2 * j][n], Xl[kq + 2 * j + 1][n]);
        #pragma unroll
        for (int j = 0; j < 4; j++) *(uint4*)(&Al[n][kq] + j * 8) = *(uint4*)(pk + j * 4);
    }
    __syncthreads();

    f32x4 qacc[2][4] = {}, kacc[2][4] = {};
    {   // stage q-weights (rows 0..127)
        int row = t >> 1, hf = t & 1;
        const uint4* src = (const uint4*)(wqkvb + (size_t)row * CIN + hf * 64);
        uint4* dst = (uint4*)&Bl[row][hf * 64];
        #pragma unroll
        for (int j = 0; j < 8; j++) dst[j] = src[j];
    }
    __syncthreads();
    #pragma unroll
    for (int ks = 0; ks < 4; ks++) {
        bf16x8 av[2], bv[4];
        #pragma unroll
        for (int i = 0; i < 2; i++) av[i] = *(const bf16x8*)&Al[wn0 + i * 16 + l15][ks * 32 + lk];
        #pragma unroll
        for (int j = 0; j < 4; j++) bv[j] = *(const bf16x8*)&Bl[wo0 + j * 16 + l15][ks * 32 + lk];
        #pragma unroll
        for (int i = 0; i < 2; i++)
            #pragma unroll
            for (int j = 0; j < 4; j++)
                qacc[i][j] = __builtin_amdgcn_mfma_f32_16x16x32_bf16(av[i], bv[j], qacc[i][j], 0, 0, 0);
    }
    __syncthreads();
    {   // stage k-weights (rows 128..255)
        int row = t >> 1, hf = t & 1;
        const uint4* src = (const uint4*)(wqkvb + (size_t)(128 + row) * CIN + hf * 64);
        uint4* dst = (uint4*)&Bl[row][hf * 64];
        #pragma unroll
        for (int j = 0; j < 8; j++) dst[j] = src[j];
    }
    __syncthreads();
    #pragma unroll
    for (int ks = 0; ks < 4; ks++) {
        bf16x8 av[2], bv[4];
        #pragma unroll
        for (int i = 0; i < 2; i++) av[i] = *(const bf16x8*)&Al[wn0 + i * 16 + l15][ks * 32 + lk];
        #pragma unroll
        for (int j = 0; j < 4; j++) bv[j] = *(const bf16x8*)&Bl[wo0 + j * 16 + l15][ks * 32 + lk];
        #pragma unroll
        for (int i = 0; i < 2; i++)
            #pragma unroll
            for (int j = 0; j < 4; j++)
                kacc[i][j] = __builtin_amdgcn_mfma_f32_16x16x32_bf16(av[i], bv[j], kacc[i][j], 0, 0, 0);
    }
    __syncthreads();  // Bl free; kTl/qTl writes may begin

    float eq[2][4][4], ek[2][4][4];
    #pragma unroll
    for (int i = 0; i < 2; i++)
        #pragma unroll
        for (int j = 0; j < 4; j++)
            #pragma unroll
            for (int r = 0; r < 4; r++) {
                eq[i][j][r] = __expf(qacc[i][j][r]);
                ek[i][j][r] = __expf(kacc[i][j][r]);
            }
    // k-softmax denominators: per (token, head) over 32 channels (16-lane groups)
    #pragma unroll
    for (int i = 0; i < 2; i++)
        #pragma unroll
        for (int r = 0; r < 4; r++) {
            float e01 = ek[i][0][r] + ek[i][1][r];
            float e23 = ek[i][2][r] + ek[i][3][r];
            #pragma unroll
            for (int m = 1; m < 16; m <<= 1) {
                e01 += __shfl_xor(e01, m);
                e23 += __shfl_xor(e23, m);
            }
            float i01 = 1.f / e01, i23 = 1.f / e23;
            ek[i][0][r] *= i01; ek[i][1][r] *= i01;
            ek[i][2][r] *= i23; ek[i][3][r] *= i23;
        }
    // transposed bf16 stores: kTl/qTl [channel][token]
    #pragma unroll
    for (int i = 0; i < 2; i++)
        #pragma unroll
        for (int j = 0; j < 4; j++) {
            int ch = wo0 + j * 16 + l15;
            int tokb = wn0 + i * 16 + (lane >> 4) * 4;
            *(unsigned*)&kTl[ch][tokb] = pack2(ek[i][j][0], ek[i][j][1]);
            *(unsigned*)&kTl[ch][tokb + 2] = pack2(ek[i][j][2], ek[i][j][3]);
            *(unsigned*)&qTl[ch][tokb] = pack2(eq[i][j][0], eq[i][j][1]);
            *(unsigned*)&qTl[ch][tokb + 2] = pack2(eq[i][j][2], eq[i][j][3]);
        }
    // qsum partials (per channel, sum over this block's 64 tokens)
    #pragma unroll
    for (int j = 0; j < 4; j++) {
        float sq = 0.f;
        #pragma unroll
        for (int i = 0; i < 2; i++)
            #pragma unroll
            for (int r = 0; r < 4; r++) sq += eq[i][j][r];
        sq += __shfl_xor(sq, 16);
        sq += __shfl_xor(sq, 32);
        if (lane < 16) sD[(wave & 1) * 128 + wo0 + j * 16 + lane] = sq;
    }
    __syncthreads();
    if (t < 128) pqsum[(size_t)bid * 128 + t] = sD[t] + sD[128 + t];
    {   // M partial = k_sm^T x e^q  (one head per wave), MFMA over 64 tokens
        f32x4 mac[2][2] = {};
        #pragma unroll
        for (int ks = 0; ks < 2; ks++) {
            bf16x8 av[2], bv[2];
            #pragma unroll
            for (int i = 0; i < 2; i++) av[i] = *(const bf16x8*)&kTl[wave * 32 + i * 16 + l15][ks * 32 + lk];
            #pragma unroll
            for (int j = 0; j < 2; j++) bv[j] = *(const bf16x8*)&qTl[wave * 32 + j * 16 + l15][ks * 32 + lk];
            #pragma unroll
            for (int i = 0; i < 2; i++)
                #pragma unroll
                for (int j = 0; j < 2; j++)
                    mac[i][j] = __builtin_amdgcn_mfma_f32_16x16x32_bf16(av[i], bv[j], mac[i][j], 0, 0, 0);
        }
        float* pmb = pM + ((size_t)bid * 4 + wave) * 1024;
        #pragma unroll
        for (int i = 0; i < 2; i++)
            #pragma unroll
            for (int j = 0; j < 2; j++)
                #pragma unroll
                for (int r = 0; r < 4; r++)
                    pmb[(i * 16 + (lane >> 4) * 4 + r) * 32 + j * 16 + l15] = mac[i][j][r];
    }
    grid.sync();

    // ================= P3: reduce M, fold into W2 (64 blocks) =============
    if (bid < 64) {
        int b3 = bid >> 2, h3 = bid & 3;
        if (t < 32) {
            float s = 0.f;
            for (int i = 0; i < 16; i++) s += pqsum[((size_t)b3 * 16 + i) * 128 + h3 * 32 + t];
            sD[t] = SCALE_Q / s;
        }
        {
            float4 m4 = { 0.f, 0.f, 0.f, 0.f };
            for (int i = 0; i < 16; i++) {
                float4 v = *(const float4*)&pM[(((size_t)b3 * 16 + i) * 4 + h3) * 1024 + t * 4];
                m4.x += v.x; m4.y += v.y; m4.z += v.z; m4.w += v.w;
            }
            *(float4*)&Ml[t >> 3][(t & 7) * 4] = m4;
        }
        __syncthreads();
        {
            int o = t >> 1, seg = t & 1;
            float wsc[32];
            #pragma unroll
            for (int c = 0; c < 32; c++) wsc[c] = wout[o * CIN + h3 * 32 + c] * sD[c];
            unsigned short* w2p = W2b + ((size_t)b3 * CIN + o) * CIN + h3 * 32 + seg * 16;
            #pragma unroll
            for (int p = 0; p < 8; p++) {
                int c0 = seg * 16 + 2 * p;
                float r0 = 0.f, r1 = 0.f;
                #pragma unroll
                for (int c = 0; c < 32; c++) {
                    r0 += wsc[c] * Ml[c0][c];
                    r1 += wsc[c] * Ml[c0 + 1][c];
                }
                *(unsigned*)(w2p + 2 * p) = pack2(r0, r1);
            }
        }
    }
    grid.sync();

    // ================= P4: V = Al x Wv ; y = W2 x V^T + bias ==============
    {   // stage v-weights (rows 256..383)
        int row = t >> 1, hf = t & 1;
        const uint4* src = (const uint4*)(wqkvb + (size_t)(256 + row) * CIN + hf * 64);
        uint4* dst = (uint4*)&Bl[row][hf * 64];
        #pragma unroll
        for (int j = 0; j < 8; j++) dst[j] = src[j];
    }
    __syncthreads();
    f32x4 vacc[2][4] = {};
    #pragma unroll
    for (int ks = 0; ks < 4; ks++) {
        bf16x8 av[2], bv[4];
        #pragma unroll
        for (int i = 0; i < 2; i++) av[i] = *(const bf16x8*)&Al[wn0 + i * 16 + l15][ks * 32 + lk];
        #pragma unroll
        for (int j = 0; j < 4; j++) bv[j] = *(const bf16x8*)&Bl[wo0 + j * 16 + l15][ks * 32 + lk];
        #pragma unroll
        for (int i = 0; i < 2; i++)
            #pragma unroll
            for (int j = 0; j < 4; j++)
                vacc[i][j] = __builtin_amdgcn_mfma_f32_16x16x32_bf16(av[i], bv[j], vacc[i][j], 0, 0, 0);
    }
    __syncthreads();  // Bl free for W2
    {   // stage W2 for this batch
        int row = t >> 1, hf = t & 1;
        const uint4* src = (const uint4*)(W2b + ((size_t)b * CIN + row) * CIN + hf * 64);
        uint4* dst = (uint4*)&Bl[row][hf * 64];
        #pragma unroll
        for (int j = 0; j < 8; j++) dst[j] = src[j];
    }
    // scatter V (bf16) -> Vl[token][vch]
    #pragma unroll
    for (int i = 0; i < 2; i++)
        #pragma unroll
        for (int j = 0; j < 4; j++) {
            int ch = wo0 + j * 16 + l15;
            #pragma unroll
            for (int r = 0; r < 4; r++)
                Vl[wn0 + i * 16 + (lane >> 4) * 4 + r][ch] = f2bf(vacc[i][j][r]);
        }
    __syncthreads();
    f32x4 yacc[4][2] = {};
    #pragma unroll
    for (int ks = 0; ks < 4; ks++) {
        bf16x8 av[4], bv[2];
        #pragma unroll
        for (int i = 0; i < 4; i++) av[i] = *(const bf16x8*)&Bl[wo0 + i * 16 + l15][ks * 32 + lk];
        #pragma unroll
        for (int j = 0; j < 2; j++) bv[j] = *(const bf16x8*)&Vl[wn0 + j * 16 + l15][ks * 32 + lk];
        #pragma unroll
        for (int i = 0; i < 4; i++)
            #pragma unroll
            for (int j = 0; j < 2; j++)
                yacc[i][j] = __builtin_amdgcn_mfma_f32_16x16x32_bf16(av[i], bv[j], yacc[i][j], 0, 0, 0);
    }
    #pragma unroll
    for (int i = 0; i < 4; i++)
        #pragma unroll
        for (int r = 0; r < 4; r++) {
            int o = wo0 + i * 16 + (lane >> 4) * 4 + r;
            float bias = bout[o];
            float* yp = y + ((size_t)b * CIN + o) * NTOK + nt * 64 + wn0;
            #pragma unroll
            for (int j = 0; j < 2; j++) yp[j * 16 + l15] = yacc[i][j][r] + bias;
        }
}

// ---------------------------------------------------------------------------
extern "C" void kernel_launch(void* const* d_in, const int* in_sizes, int n_in,
                              void* d_out, int out_size, void* d_ws, size_t ws_size,
                              hipStream_t stream) {
    const float* x = (const float*)d_in[0];
    const float* gw = (const float*)d_in[1];
    const float* gb = (const float*)d_in[2];
    const float* wqkv = (const float*)d_in[3];
    const float* wout = (const float*)d_in[4];
    const float* bout = (const float*)d_in[5];
    float* y = (float*)d_out;
    float* ws = (float*)d_ws;
    void* args[] = { &x, &gw, &gb, &wqkv, &wout, &bout, &y, &ws };
    hipLaunchCooperativeKernel((const void*)k_fused, dim3(256), dim3(256), args, 0, stream);
}

// Round 4
// 93.519 us; speedup vs baseline: 2.0610x; 2.0610x over previous
//
#include <hip/hip_runtime.h>
#include <math.h>

// B=16, C=128, N=1024, HEADS=4, DIM_HEAD=32. qkv rows = 384.
#define CIN 128
#define NTOK 1024
#define SCALE_Q 0.17677669529663687f /* 32^-0.5 */
#define GN_EPS 1e-5f
#define PB (CIN * NTOK) /* 131072 */

// ---- workspace layout (float units), all plain stores (no init needed) ----
// wqkvb  bf16 [384][128]          @0        (24576 fl)
// pstats f32  [256][2]            @24576    (512 fl)
// pqsum  f32  [256][128]          @25088    (32768 fl)
// Vst    bf16 [16][1024][128]     @57856    (1048576 fl)
// pM     f32  [256][4][32][32]    @1106432  (1048576 fl)
#define WS_WQKVB 0
#define WS_PSTATS 24576
#define WS_PQSUM 25088
#define WS_VST 57856
#define WS_PM 1106432

typedef __bf16 bf16x8 __attribute__((ext_vector_type(8)));
typedef float f32x4 __attribute__((ext_vector_type(4)));

__device__ __forceinline__ unsigned short f2bf(float f) {
    union { float f; unsigned u; } v; v.f = f;
    unsigned r = v.u + 0x7fffu + ((v.u >> 16) & 1u);
    return (unsigned short)(r >> 16);
}
__device__ __forceinline__ unsigned pack2(float a, float b) {
    return (unsigned)f2bf(a) | ((unsigned)f2bf(b) << 16);
}

// ---------------------------------------------------------------------------
// K1: per-32KB-chunk stats partials + wqkv -> bf16. grid 256.
__global__ __launch_bounds__(256) void k_pre(const float* __restrict__ x,
                                             const float* __restrict__ wqkv,
                                             float* __restrict__ ws) {
    float* pstats = ws + WS_PSTATS;
    unsigned short* wqkvb = (unsigned short*)(ws + WS_WQKVB);
    __shared__ float sD[8];
    int bid = blockIdx.x, t = threadIdx.x;
    int lane = t & 63, wave = t >> 6;
    const float4* p = (const float4*)(x + (size_t)bid * 8192);
    float s = 0.f, s2 = 0.f;
    #pragma unroll
    for (int i = 0; i < 8; i++) {
        float4 v = p[t + 256 * i];
        s += v.x + v.y + v.z + v.w;
        s2 += v.x * v.x + v.y * v.y + v.z * v.z + v.w * v.w;
    }
    #pragma unroll
    for (int off = 32; off; off >>= 1) {
        s += __shfl_down(s, off);
        s2 += __shfl_down(s2, off);
    }
    if (lane == 0) { sD[wave * 2] = s; sD[wave * 2 + 1] = s2; }
    if (bid < 48) {
        float4 v = ((const float4*)(wqkv + bid * 1024))[t];
        uint2 pk2; pk2.x = pack2(v.x, v.y); pk2.y = pack2(v.z, v.w);
        *(uint2*)(wqkvb + bid * 1024 + t * 4) = pk2;
    }
    __syncthreads();
    if (t == 0) {
        pstats[bid * 2] = sD[0] + sD[2] + sD[4] + sD[6];
        pstats[bid * 2 + 1] = sD[1] + sD[3] + sD[5] + sD[7];
    }
}

// ---------------------------------------------------------------------------
// K2: per (b, 64-token tile): GN -> Al(bf16); q,k MFMA; exp + k-softmax;
// qsum partials; M partials (MFMA); V = Al x Wv (MFMA) -> Vst bf16.
// grid 256 (= b*16 + nt), 256 thr.
// LDS: Al[64][136]@0 | Xl f32[128][68] / Bl[128][136] / kTl[128][72] @17408 |
//      qTl[128][72] / Vl[64][136] @52224 | sD f32[256] @70656
__global__ __launch_bounds__(256, 1) void k_qkvm(const float* __restrict__ x,
                                                 const float* __restrict__ gw,
                                                 const float* __restrict__ gb,
                                                 float* __restrict__ ws) {
    __shared__ __align__(16) char smem[71680];
    unsigned short (*Al)[136] = (unsigned short(*)[136])smem;
    float (*Xl)[68] = (float(*)[68])(smem + 17408);
    unsigned short (*Bl)[136] = (unsigned short(*)[136])(smem + 17408);
    unsigned short (*kTl)[72] = (unsigned short(*)[72])(smem + 17408);
    unsigned short (*qTl)[72] = (unsigned short(*)[72])(smem + 52224);
    unsigned short (*Vl)[136] = (unsigned short(*)[136])(smem + 52224);
    float* sD = (float*)(smem + 70656);

    unsigned short* wqkvb = (unsigned short*)(ws + WS_WQKVB);
    float* pstats = ws + WS_PSTATS;
    float* pqsum = ws + WS_PQSUM;
    unsigned short* Vst = (unsigned short*)(ws + WS_VST);
    float* pM = ws + WS_PM;

    int bid = blockIdx.x, t = threadIdx.x;
    int b = bid >> 4, nt = bid & 15;
    int lane = t & 63, wave = t >> 6;
    int l15 = lane & 15, lk = (lane >> 4) * 8;
    int wn0 = (wave & 1) * 32, wo0 = (wave >> 1) * 64;

    if (t < 32) sD[t] = pstats[b * 32 + t];
    __syncthreads();
    float mu, rsv;
    {
        float s = 0.f, s2 = 0.f;
        #pragma unroll
        for (int i = 0; i < 16; i++) { s += sD[2 * i]; s2 += sD[2 * i + 1]; }
        mu = s * (1.f / PB);
        float var = s2 * (1.f / PB) - mu * mu;
        rsv = rsqrtf(var + GN_EPS);
    }
    {   // stage x rows with GN applied
        int c = t >> 1, hf = t & 1;
        float g = gw[c] * rsv, bb = gb[c] - mu * g;
        const float4* src = (const float4*)(x + ((size_t)b * CIN + c) * NTOK + nt * 64 + hf * 32);
        #pragma unroll
        for (int i = 0; i < 8; i++) {
            float4 v = src[i];
            float4 r = { v.x * g + bb, v.y * g + bb, v.z * g + bb, v.w * g + bb };
            *(float4*)&Xl[c][hf * 32 + i * 4] = r;
        }
    }
    __syncthreads();
    {   // transpose + bf16 pack -> Al[n][c]
        int n = t & 63, kq = (t >> 6) * 32;
        unsigned pk[16];
        #pragma unroll
        for (int j = 0; j < 16; j++) pk[j] = pack2(Xl[kq + 2 * j][n], Xl[kq + 2 * j + 1][n]);
        #pragma unroll
        for (int j = 0; j < 4; j++) *(uint4*)(&Al[n][kq] + j * 8) = *(uint4*)(pk + j * 4);
    }
    __syncthreads();

    f32x4 qacc[2][4] = {}, kacc[2][4] = {};
    {   // stage q-weights (rows 0..127)
        int row = t >> 1, hf = t & 1;
        const uint4* src = (const uint4*)(wqkvb + (size_t)row * CIN + hf * 64);
        uint4* dst = (uint4*)&Bl[row][hf * 64];
        #pragma unroll
        for (int j = 0; j < 8; j++) dst[j] = src[j];
    }
    __syncthreads();
    #pragma unroll
    for (int ks = 0; ks < 4; ks++) {
        bf16x8 av[2], bv[4];
        #pragma unroll
        for (int i = 0; i < 2; i++) av[i] = *(const bf16x8*)&Al[wn0 + i * 16 + l15][ks * 32 + lk];
        #pragma unroll
        for (int j = 0; j < 4; j++) bv[j] = *(const bf16x8*)&Bl[wo0 + j * 16 + l15][ks * 32 + lk];
        #pragma unroll
        for (int i = 0; i < 2; i++)
            #pragma unroll
            for (int j = 0; j < 4; j++)
                qacc[i][j] = __builtin_amdgcn_mfma_f32_16x16x32_bf16(av[i], bv[j], qacc[i][j], 0, 0, 0);
    }
    __syncthreads();
    {   // stage k-weights (rows 128..255)
        int row = t >> 1, hf = t & 1;
        const uint4* src = (const uint4*)(wqkvb + (size_t)(128 + row) * CIN + hf * 64);
        uint4* dst = (uint4*)&Bl[row][hf * 64];
        #pragma unroll
        for (int j = 0; j < 8; j++) dst[j] = src[j];
    }
    __syncthreads();
    #pragma unroll
    for (int ks = 0; ks < 4; ks++) {
        bf16x8 av[2], bv[4];
        #pragma unroll
        for (int i = 0; i < 2; i++) av[i] = *(const bf16x8*)&Al[wn0 + i * 16 + l15][ks * 32 + lk];
        #pragma unroll
        for (int j = 0; j < 4; j++) bv[j] = *(const bf16x8*)&Bl[wo0 + j * 16 + l15][ks * 32 + lk];
        #pragma unroll
        for (int i = 0; i < 2; i++)
            #pragma unroll
            for (int j = 0; j < 4; j++)
                kacc[i][j] = __builtin_amdgcn_mfma_f32_16x16x32_bf16(av[i], bv[j], kacc[i][j], 0, 0, 0);
    }
    __syncthreads();  // Bl reads done; kTl/qTl writes may begin

    float eq[2][4][4], ek[2][4][4];
    #pragma unroll
    for (int i = 0; i < 2; i++)
        #pragma unroll
        for (int j = 0; j < 4; j++)
            #pragma unroll
            for (int r = 0; r < 4; r++) {
                eq[i][j][r] = __expf(qacc[i][j][r]);
                ek[i][j][r] = __expf(kacc[i][j][r]);
            }
    // k-softmax denominators: per (token, head) over 32 channels (16-lane groups)
    #pragma unroll
    for (int i = 0; i < 2; i++)
        #pragma unroll
        for (int r = 0; r < 4; r++) {
            float e01 = ek[i][0][r] + ek[i][1][r];
            float e23 = ek[i][2][r] + ek[i][3][r];
            #pragma unroll
            for (int m = 1; m < 16; m <<= 1) {
                e01 += __shfl_xor(e01, m);
                e23 += __shfl_xor(e23, m);
            }
            float i01 = 1.f / e01, i23 = 1.f / e23;
            ek[i][0][r] *= i01; ek[i][1][r] *= i01;
            ek[i][2][r] *= i23; ek[i][3][r] *= i23;
        }
    // transposed bf16 stores: kTl/qTl [channel][token]
    #pragma unroll
    for (int i = 0; i < 2; i++)
        #pragma unroll
        for (int j = 0; j < 4; j++) {
            int ch = wo0 + j * 16 + l15;
            int tokb = wn0 + i * 16 + (lane >> 4) * 4;
            *(unsigned*)&kTl[ch][tokb] = pack2(ek[i][j][0], ek[i][j][1]);
            *(unsigned*)&kTl[ch][tokb + 2] = pack2(ek[i][j][2], ek[i][j][3]);
            *(unsigned*)&qTl[ch][tokb] = pack2(eq[i][j][0], eq[i][j][1]);
            *(unsigned*)&qTl[ch][tokb + 2] = pack2(eq[i][j][2], eq[i][j][3]);
        }
    // qsum partials (per channel, sum over this block's 64 tokens)
    #pragma unroll
    for (int j = 0; j < 4; j++) {
        float sq = 0.f;
        #pragma unroll
        for (int i = 0; i < 2; i++)
            #pragma unroll
            for (int r = 0; r < 4; r++) sq += eq[i][j][r];
        sq += __shfl_xor(sq, 16);
        sq += __shfl_xor(sq, 32);
        if (lane < 16) sD[(wave & 1) * 128 + wo0 + j * 16 + lane] = sq;
    }
    __syncthreads();
    if (t < 128) pqsum[(size_t)bid * 128 + t] = sD[t] + sD[128 + t];
    {   // M partial = k_sm^T x e^q (one head per wave), MFMA over 64 tokens
        f32x4 mac[2][2] = {};
        #pragma unroll
        for (int ks = 0; ks < 2; ks++) {
            bf16x8 av[2], bv[2];
            #pragma unroll
            for (int i = 0; i < 2; i++) av[i] = *(const bf16x8*)&kTl[wave * 32 + i * 16 + l15][ks * 32 + lk];
            #pragma unroll
            for (int j = 0; j < 2; j++) bv[j] = *(const bf16x8*)&qTl[wave * 32 + j * 16 + l15][ks * 32 + lk];
            #pragma unroll
            for (int i = 0; i < 2; i++)
                #pragma unroll
                for (int j = 0; j < 2; j++)
                    mac[i][j] = __builtin_amdgcn_mfma_f32_16x16x32_bf16(av[i], bv[j], mac[i][j], 0, 0, 0);
        }
        float* pmb = pM + ((size_t)bid * 4 + wave) * 1024;
        #pragma unroll
        for (int i = 0; i < 2; i++)
            #pragma unroll
            for (int j = 0; j < 2; j++)
                #pragma unroll
                for (int r = 0; r < 4; r++)
                    pmb[(i * 16 + (lane >> 4) * 4 + r) * 32 + j * 16 + l15] = mac[i][j][r];
    }
    __syncthreads();  // all M-MFMA LDS reads done

    {   // stage v-weights (rows 256..383)
        int row = t >> 1, hf = t & 1;
        const uint4* src = (const uint4*)(wqkvb + (size_t)(256 + row) * CIN + hf * 64);
        uint4* dst = (uint4*)&Bl[row][hf * 64];
        #pragma unroll
        for (int j = 0; j < 8; j++) dst[j] = src[j];
    }
    __syncthreads();
    f32x4 vacc[2][4] = {};
    #pragma unroll
    for (int ks = 0; ks < 4; ks++) {
        bf16x8 av[2], bv[4];
        #pragma unroll
        for (int i = 0; i < 2; i++) av[i] = *(const bf16x8*)&Al[wn0 + i * 16 + l15][ks * 32 + lk];
        #pragma unroll
        for (int j = 0; j < 4; j++) bv[j] = *(const bf16x8*)&Bl[wo0 + j * 16 + l15][ks * 32 + lk];
        #pragma unroll
        for (int i = 0; i < 2; i++)
            #pragma unroll
            for (int j = 0; j < 4; j++)
                vacc[i][j] = __builtin_amdgcn_mfma_f32_16x16x32_bf16(av[i], bv[j], vacc[i][j], 0, 0, 0);
    }
    // scatter V (bf16) -> Vl[token][vch]  (qTl region; safe after M-MFMA sync)
    #pragma unroll
    for (int i = 0; i < 2; i++)
        #pragma unroll
        for (int j = 0; j < 4; j++) {
            int ch = wo0 + j * 16 + l15;
            #pragma unroll
            for (int r = 0; r < 4; r++)
                Vl[wn0 + i * 16 + (lane >> 4) * 4 + r][ch] = f2bf(vacc[i][j][r]);
        }
    __syncthreads();
    {   // linear store Vl -> Vst[bid*64 ..][128]
        int row = t >> 2, q = t & 3;
        const uint4* src = (const uint4*)&Vl[row][q * 32];
        uint4* dst = (uint4*)(Vst + ((size_t)bid * 64 + row) * CIN + q * 32);
        #pragma unroll
        for (int j = 0; j < 4; j++) dst[j] = src[j];
    }
}

// ---------------------------------------------------------------------------
// K3: per (b, nt): reduce pqsum -> qinv; reduce pM -> Mt bf16; u = V x Mt (MFMA);
// y = (wout * qinv) x u^T + bias (MFMA). grid 256, 256 thr.
// LDS: Wl[128][136]@0 | Ul[64][136]@34816 | Vl[64][136]@52224 |
//      Mt bf16[4][32][40]@69632 | sD f32[128]@79872
__global__ __launch_bounds__(256, 1) void k_out(const float* __restrict__ wout,
                                                const float* __restrict__ bout,
                                                float* __restrict__ ws,
                                                float* __restrict__ y) {
    __shared__ __align__(16) char smem[80384];
    unsigned short (*Wl)[136] = (unsigned short(*)[136])smem;
    unsigned short (*Ul)[136] = (unsigned short(*)[136])(smem + 34816);
    unsigned short (*Vl)[136] = (unsigned short(*)[136])(smem + 52224);
    unsigned short (*Mt)[32][40] = (unsigned short(*)[32][40])(smem + 69632);
    float* sD = (float*)(smem + 79872);

    float* pqsum = ws + WS_PQSUM;
    unsigned short* Vst = (unsigned short*)(ws + WS_VST);
    float* pM = ws + WS_PM;

    int bid = blockIdx.x, t = threadIdx.x;
    int b = bid >> 4, nt = bid & 15;
    int lane = t & 63, wave = t >> 6;
    int l15 = lane & 15, lk = (lane >> 4) * 8;
    int wn0 = (wave & 1) * 32, wo0 = (wave >> 1) * 64;

    // qinv = SCALE_Q / sum_nt pqsum
    if (t < 128) {
        float s = 0.f;
        #pragma unroll
        for (int i = 0; i < 16; i++) s += pqsum[((size_t)(b * 16 + i)) * 128 + t];
        sD[t] = SCALE_Q / s;
    }
    {   // stage V tile
        int row = t >> 2, q = t & 3;
        const uint4* src = (const uint4*)(Vst + ((size_t)bid * 64 + row) * CIN + q * 32);
        uint4* dst = (uint4*)&Vl[row][q * 32];
        #pragma unroll
        for (int j = 0; j < 4; j++) dst[j] = src[j];
    }
    // reduce pM over the batch's 16 tiles -> Mt[h][c][c'] (transposed, bf16)
    #pragma unroll
    for (int s4 = 0; s4 < 4; s4++) {
        int slot = t + (s4 << 8);          // 0..1023
        int h = slot >> 8, cp = (slot >> 3) & 31, c4 = slot & 7;
        float4 m = { 0.f, 0.f, 0.f, 0.f };
        for (int i = 0; i < 16; i++) {
            const float4 v = *(const float4*)&pM[(((size_t)(b * 16 + i)) * 4 + h) * 1024 + cp * 32 + c4 * 4];
            m.x += v.x; m.y += v.y; m.z += v.z; m.w += v.w;
        }
        Mt[h][c4 * 4 + 0][cp] = f2bf(m.x);
        Mt[h][c4 * 4 + 1][cp] = f2bf(m.y);
        Mt[h][c4 * 4 + 2][cp] = f2bf(m.z);
        Mt[h][c4 * 4 + 3][cp] = f2bf(m.w);
    }
    __syncthreads();

    // u[n][c] = sum_c' v[n][c'] * M[c'][c]   (wave = head, 64x32, K=32)
    f32x4 uac[4][2] = {};
    {
        bf16x8 mv[2];
        #pragma unroll
        for (int j = 0; j < 2; j++) mv[j] = *(const bf16x8*)&Mt[wave][j * 16 + l15][lk];
        #pragma unroll
        for (int i = 0; i < 4; i++) {
            bf16x8 av = *(const bf16x8*)&Vl[i * 16 + l15][wave * 32 + lk];
            #pragma unroll
            for (int j = 0; j < 2; j++)
                uac[i][j] = __builtin_amdgcn_mfma_f32_16x16x32_bf16(av, mv[j], uac[i][j], 0, 0, 0);
        }
    }
    {   // stage wout scaled by qinv -> Wl bf16
        int o = t >> 1, hf = t & 1;
        const float4* src = (const float4*)(wout + (size_t)o * CIN + hf * 64);
        unsigned pk[32];
        #pragma unroll
        for (int i = 0; i < 16; i++) {
            float4 v = src[i];
            int c = hf * 64 + i * 4;
            v.x *= sD[c]; v.y *= sD[c + 1]; v.z *= sD[c + 2]; v.w *= sD[c + 3];
            pk[2 * i] = pack2(v.x, v.y);
            pk[2 * i + 1] = pack2(v.z, v.w);
        }
        uint4* dst = (uint4*)&Wl[o][hf * 64];
        #pragma unroll
        for (int j = 0; j < 8; j++) dst[j] = *(uint4*)(pk + j * 4);
    }
    // scatter u -> Ul[n][h*32+c]
    #pragma unroll
    for (int i = 0; i < 4; i++)
        #pragma unroll
        for (int j = 0; j < 2; j++) {
            int ch = wave * 32 + j * 16 + l15;
            #pragma unroll
            for (int r = 0; r < 4; r++)
                Ul[i * 16 + (lane >> 4) * 4 + r][ch] = f2bf(uac[i][j][r]);
        }
    __syncthreads();

    // y = Wl x Ul^T + bias
    f32x4 yacc[4][2] = {};
    #pragma unroll
    for (int ks = 0; ks < 4; ks++) {
        bf16x8 av[4], bv[2];
        #pragma unroll
        for (int i = 0; i < 4; i++) av[i] = *(const bf16x8*)&Wl[wo0 + i * 16 + l15][ks * 32 + lk];
        #pragma unroll
        for (int j = 0; j < 2; j++) bv[j] = *(const bf16x8*)&Ul[wn0 + j * 16 + l15][ks * 32 + lk];
        #pragma unroll
        for (int i = 0; i < 4; i++)
            #pragma unroll
            for (int j = 0; j < 2; j++)
                yacc[i][j] = __builtin_amdgcn_mfma_f32_16x16x32_bf16(av[i], bv[j], yacc[i][j], 0, 0, 0);
    }
    #pragma unroll
    for (int i = 0; i < 4; i++)
        #pragma unroll
        for (int r = 0; r < 4; r++) {
            int o = wo0 + i * 16 + (lane >> 4) * 4 + r;
            float bias = bout[o];
            float* yp = y + ((size_t)b * CIN + o) * NTOK + nt * 64 + wn0;
            #pragma unroll
            for (int j = 0; j < 2; j++) yp[j * 16 + l15] = yacc[i][j][r] + bias;
        }
}

// ---------------------------------------------------------------------------
extern "C" void kernel_launch(void* const* d_in, const int* in_sizes, int n_in,
                              void* d_out, int out_size, void* d_ws, size_t ws_size,
                              hipStream_t stream) {
    const float* x = (const float*)d_in[0];
    const float* gw = (const float*)d_in[1];
    const float* gb = (const float*)d_in[2];
    const float* wqkv = (const float*)d_in[3];
    const float* wout = (const float*)d_in[4];
    const float* bout = (const float*)d_in[5];
    float* y = (float*)d_out;
    float* ws = (float*)d_ws;

    k_pre<<<dim3(256), 256, 0, stream>>>(x, wqkv, ws);
    k_qkvm<<<dim3(256), 256, 0, stream>>>(x, gw, gb, ws);
    k_out<<<dim3(256), 256, 0, stream>>>(wout, bout, ws, y);
}

// Round 5
// 92.901 us; speedup vs baseline: 2.0747x; 1.0066x over previous
//
#include <hip/hip_runtime.h>
#include <math.h>

// B=16, C=128, N=1024, HEADS=4, DIM_HEAD=32. qkv rows = 384.
#define CIN 128
#define NTOK 1024
#define SCALE_Q 0.17677669529663687f /* 32^-0.5 */
#define GN_EPS 1e-5f
#define PB (CIN * NTOK) /* 131072 */

// ---- workspace layout (float units), all plain stores (no init needed) ----
#define WS_WQKVB 0        /* bf16 [384][128]      (24576 fl) */
#define WS_PSTATS 24576   /* f32  [256][2]        (512 fl)   */
#define WS_PQSUM 25088    /* f32  [256][128]      (32768 fl) */
#define WS_VST 57856      /* bf16 [16][1024][128] (1048576 fl) */
#define WS_PM 1106432     /* f32  [256][4][32][32](1048576 fl) */

typedef __bf16 bf16x8 __attribute__((ext_vector_type(8)));
typedef float f32x4 __attribute__((ext_vector_type(4)));

__device__ __forceinline__ unsigned short f2bf(float f) {
    union { float f; unsigned u; } v; v.f = f;
    unsigned r = v.u + 0x7fffu + ((v.u >> 16) & 1u);
    return (unsigned short)(r >> 16);
}
__device__ __forceinline__ unsigned pack2(float a, float b) {
    return (unsigned)f2bf(a) | ((unsigned)f2bf(b) << 16);
}

// ---------------------------------------------------------------------------
// K1: per-32KB-chunk stats partials + wqkv -> bf16. grid 256 x 256.
__global__ __launch_bounds__(256) void k_pre(const float* __restrict__ x,
                                             const float* __restrict__ wqkv,
                                             float* __restrict__ ws) {
    float* pstats = ws + WS_PSTATS;
    unsigned short* wqkvb = (unsigned short*)(ws + WS_WQKVB);
    __shared__ float sD[8];
    int bid = blockIdx.x, t = threadIdx.x;
    int lane = t & 63, wave = t >> 6;
    const float4* p = (const float4*)(x + (size_t)bid * 8192);
    float s = 0.f, s2 = 0.f;
    #pragma unroll
    for (int i = 0; i < 8; i++) {
        float4 v = p[t + 256 * i];
        s += v.x + v.y + v.z + v.w;
        s2 += v.x * v.x + v.y * v.y + v.z * v.z + v.w * v.w;
    }
    #pragma unroll
    for (int off = 32; off; off >>= 1) {
        s += __shfl_down(s, off);
        s2 += __shfl_down(s2, off);
    }
    if (lane == 0) { sD[wave * 2] = s; sD[wave * 2 + 1] = s2; }
    if (bid < 48) {
        float4 v = ((const float4*)(wqkv + bid * 1024))[t];
        uint2 pk2; pk2.x = pack2(v.x, v.y); pk2.y = pack2(v.z, v.w);
        *(uint2*)(wqkvb + bid * 1024 + t * 4) = pk2;
    }
    __syncthreads();
    if (t == 0) {
        pstats[bid * 2] = sD[0] + sD[2] + sD[4] + sD[6];
        pstats[bid * 2 + 1] = sD[1] + sD[3] + sD[5] + sD[7];
    }
}

// ---------------------------------------------------------------------------
// K2: per (b, 64-token tile), 512 threads (8 waves = 2 waves/SIMD).
// GN -> Al(bf16); q+k MFMA (one pass, 256 rows); exp + k-softmax; qsum
// partials; M partials (waves 0-3) || v-weight stage (waves 4-7); V MFMA ->
// Vst bf16.  grid 256.
// LDS: Al[64][136]@0 | Bl[256][136]@17408 (Xl f32[128][68] aliased) |
//      kTl[128][72]@87040 (Vl[64][136] aliased) | qTl[128][72]@105472 |
//      sD f32[256]@123904.  total 124928 B.
__global__ __launch_bounds__(512, 1) void k_qkvm(const float* __restrict__ x,
                                                 const float* __restrict__ gw,
                                                 const float* __restrict__ gb,
                                                 float* __restrict__ ws) {
    __shared__ __align__(16) char smem[124928];
    unsigned short (*Al)[136] = (unsigned short(*)[136])smem;
    unsigned short (*Bl)[136] = (unsigned short(*)[136])(smem + 17408);
    float (*Xl)[68] = (float(*)[68])(smem + 17408);
    unsigned short (*kTl)[72] = (unsigned short(*)[72])(smem + 87040);
    unsigned short (*Vl)[136] = (unsigned short(*)[136])(smem + 87040);
    unsigned short (*qTl)[72] = (unsigned short(*)[72])(smem + 105472);
    float* sD = (float*)(smem + 123904);

    unsigned short* wqkvb = (unsigned short*)(ws + WS_WQKVB);
    float* pstats = ws + WS_PSTATS;
    float* pqsum = ws + WS_PQSUM;
    unsigned short* Vst = (unsigned short*)(ws + WS_VST);
    float* pM = ws + WS_PM;

    int bid = blockIdx.x, t = threadIdx.x;
    int b = bid >> 4, nt = bid & 15;
    int lane = t & 63, wave = t >> 6;
    int l15 = lane & 15, lk = (lane >> 4) * 8;
    int sel = wave >> 1;            // 0..3: output-row quadrant (q:0,1  k:2,3)
    int wn0 = (wave & 1) * 32;      // token half

    if (t < 32) sD[t] = pstats[b * 32 + t];
    __syncthreads();
    float mu, rsv;
    {
        float s = 0.f, s2 = 0.f;
        #pragma unroll
        for (int i = 0; i < 16; i++) { s += sD[2 * i]; s2 += sD[2 * i + 1]; }
        mu = s * (1.f / PB);
        float var = s2 * (1.f / PB) - mu * mu;
        rsv = rsqrtf(var + GN_EPS);
    }
    {   // stage x rows with GN applied (c = t>>2, quarter = t&3)
        int c = t >> 2, qtr = t & 3;
        float g = gw[c] * rsv, bb = gb[c] - mu * g;
        const float4* src = (const float4*)(x + ((size_t)b * CIN + c) * NTOK + nt * 64 + qtr * 16);
        #pragma unroll
        for (int i = 0; i < 4; i++) {
            float4 v = src[i];
            float4 r = { v.x * g + bb, v.y * g + bb, v.z * g + bb, v.w * g + bb };
            *(float4*)&Xl[c][qtr * 16 + i * 4] = r;
        }
    }
    __syncthreads();
    {   // transpose + bf16 pack -> Al[n][c]  (n = t&63, 16-ch group = t>>6)
        int n = t & 63, kq = (t >> 6) * 16;
        unsigned pk[8];
        #pragma unroll
        for (int j = 0; j < 8; j++) pk[j] = pack2(Xl[kq + 2 * j][n], Xl[kq + 2 * j + 1][n]);
        *(uint4*)&Al[n][kq] = *(uint4*)pk;
        *(uint4*)(&Al[n][kq] + 8) = *(uint4*)(pk + 4);
    }
    __syncthreads();
    {   // stage q+k weights (rows 0..255) in one pass
        int row = t >> 1, hf = t & 1;
        const uint4* src = (const uint4*)(wqkvb + (size_t)row * CIN + hf * 64);
        uint4* dst = (uint4*)&Bl[row][hf * 64];
        #pragma unroll
        for (int j = 0; j < 8; j++) dst[j] = src[j];
    }
    __syncthreads();

    // q/k MFMA: wave covers rows sel*64..+63, tokens wn0..wn0+31
    f32x4 acc[2][4] = {};
    #pragma unroll
    for (int ks = 0; ks < 4; ks++) {
        bf16x8 av[2], bv[4];
        #pragma unroll
        for (int i = 0; i < 2; i++) av[i] = *(const bf16x8*)&Al[wn0 + i * 16 + l15][ks * 32 + lk];
        #pragma unroll
        for (int j = 0; j < 4; j++) bv[j] = *(const bf16x8*)&Bl[sel * 64 + j * 16 + l15][ks * 32 + lk];
        #pragma unroll
        for (int i = 0; i < 2; i++)
            #pragma unroll
            for (int j = 0; j < 4; j++)
                acc[i][j] = __builtin_amdgcn_mfma_f32_16x16x32_bf16(av[i], bv[j], acc[i][j], 0, 0, 0);
    }

    float e[2][4][4];
    #pragma unroll
    for (int i = 0; i < 2; i++)
        #pragma unroll
        for (int j = 0; j < 4; j++)
            #pragma unroll
            for (int r = 0; r < 4; r++) e[i][j][r] = __expf(acc[i][j][r]);

    if (sel >= 2) {
        // k rows: softmax over each head's 32 channels (16-lane groups)
        #pragma unroll
        for (int i = 0; i < 2; i++)
            #pragma unroll
            for (int r = 0; r < 4; r++) {
                float e01 = e[i][0][r] + e[i][1][r];
                float e23 = e[i][2][r] + e[i][3][r];
                #pragma unroll
                for (int m = 1; m < 16; m <<= 1) {
                    e01 += __shfl_xor(e01, m);
                    e23 += __shfl_xor(e23, m);
                }
                float i01 = 1.f / e01, i23 = 1.f / e23;
                e[i][0][r] *= i01; e[i][1][r] *= i01;
                e[i][2][r] *= i23; e[i][3][r] *= i23;
            }
        #pragma unroll
        for (int i = 0; i < 2; i++)
            #pragma unroll
            for (int j = 0; j < 4; j++) {
                int ch = (sel - 2) * 64 + j * 16 + l15;
                int tokb = wn0 + i * 16 + (lane >> 4) * 4;
                *(unsigned*)&kTl[ch][tokb] = pack2(e[i][j][0], e[i][j][1]);
                *(unsigned*)&kTl[ch][tokb + 2] = pack2(e[i][j][2], e[i][j][3]);
            }
    } else {
        // q rows: transposed store + per-channel partial sums
        #pragma unroll
        for (int i = 0; i < 2; i++)
            #pragma unroll
            for (int j = 0; j < 4; j++) {
                int ch = sel * 64 + j * 16 + l15;
                int tokb = wn0 + i * 16 + (lane >> 4) * 4;
                *(unsigned*)&qTl[ch][tokb] = pack2(e[i][j][0], e[i][j][1]);
                *(unsigned*)&qTl[ch][tokb + 2] = pack2(e[i][j][2], e[i][j][3]);
            }
        #pragma unroll
        for (int j = 0; j < 4; j++) {
            float sq = 0.f;
            #pragma unroll
            for (int i = 0; i < 2; i++)
                #pragma unroll
                for (int r = 0; r < 4; r++) sq += e[i][j][r];
            sq += __shfl_xor(sq, 16);
            sq += __shfl_xor(sq, 32);
            if (lane < 16) sD[(wave & 1) * 128 + sel * 64 + j * 16 + lane] = sq;
        }
    }
    __syncthreads();
    if (t < 128) pqsum[(size_t)bid * 128 + t] = sD[t] + sD[128 + t];

    if (wave < 4) {  // M partial = k_sm^T x e^q (head = wave), K=64
        int h = wave;
        f32x4 mac[2][2] = {};
        #pragma unroll
        for (int ks = 0; ks < 2; ks++) {
            bf16x8 av[2], bv[2];
            #pragma unroll
            for (int i = 0; i < 2; i++) av[i] = *(const bf16x8*)&kTl[h * 32 + i * 16 + l15][ks * 32 + lk];
            #pragma unroll
            for (int j = 0; j < 2; j++) bv[j] = *(const bf16x8*)&qTl[h * 32 + j * 16 + l15][ks * 32 + lk];
            #pragma unroll
            for (int i = 0; i < 2; i++)
                #pragma unroll
                for (int j = 0; j < 2; j++)
                    mac[i][j] = __builtin_amdgcn_mfma_f32_16x16x32_bf16(av[i], bv[j], mac[i][j], 0, 0, 0);
        }
        float* pmb = pM + ((size_t)bid * 4 + h) * 1024;
        #pragma unroll
        for (int i = 0; i < 2; i++)
            #pragma unroll
            for (int j = 0; j < 2; j++)
                #pragma unroll
                for (int r = 0; r < 4; r++)
                    pmb[(i * 16 + (lane >> 4) * 4 + r) * 32 + j * 16 + l15] = mac[i][j][r];
    } else {  // stage v-weights (rows 256..383) into Bl rows 0..127
        int t2 = t - 256;
        int row = t2 >> 1, hf = t2 & 1;
        const uint4* src = (const uint4*)(wqkvb + (size_t)(256 + row) * CIN + hf * 64);
        uint4* dst = (uint4*)&Bl[row][hf * 64];
        #pragma unroll
        for (int j = 0; j < 8; j++) dst[j] = src[j];
    }
    __syncthreads();  // v-weights ready; kTl/qTl reads done (Vl region writable)

    {   // V = Al x Wv : wave covers v-ch slice (wave>>1)*32, tokens wn0
        int wo0v = sel * 32;
        f32x4 vacc[2][2] = {};
        #pragma unroll
        for (int ks = 0; ks < 4; ks++) {
            bf16x8 av[2], bv[2];
            #pragma unroll
            for (int i = 0; i < 2; i++) av[i] = *(const bf16x8*)&Al[wn0 + i * 16 + l15][ks * 32 + lk];
            #pragma unroll
            for (int j = 0; j < 2; j++) bv[j] = *(const bf16x8*)&Bl[wo0v + j * 16 + l15][ks * 32 + lk];
            #pragma unroll
            for (int i = 0; i < 2; i++)
                #pragma unroll
                for (int j = 0; j < 2; j++)
                    vacc[i][j] = __builtin_amdgcn_mfma_f32_16x16x32_bf16(av[i], bv[j], vacc[i][j], 0, 0, 0);
        }
        #pragma unroll
        for (int i = 0; i < 2; i++)
            #pragma unroll
            for (int j = 0; j < 2; j++) {
                int ch = wo0v + j * 16 + l15;
                #pragma unroll
                for (int r = 0; r < 4; r++)
                    Vl[wn0 + i * 16 + (lane >> 4) * 4 + r][ch] = f2bf(vacc[i][j][r]);
            }
    }
    __syncthreads();
    {   // linear store Vl -> Vst
        int row = t >> 3, qq = t & 7;
        uint4* dst = (uint4*)(Vst + ((size_t)bid * 64 + row) * CIN + qq * 16);
        dst[0] = *(uint4*)&Vl[row][qq * 16];
        dst[1] = *(uint4*)&Vl[row][qq * 16 + 8];
    }
}

// ---------------------------------------------------------------------------
// K3: per (b, nt), 512 threads: reduce pqsum -> qinv; reduce pM -> Mt bf16;
// u = V x Mt (MFMA); y = (wout*qinv) x u^T + bias (MFMA). grid 256.
// LDS: Wl[128][136]@0 | Ul[64][136]@34816 | Vl[64][136]@52224 |
//      Mt[4][32][40]@69632 | sD f32[128]@79872. total 80384 B.
__global__ __launch_bounds__(512, 1) void k_out(const float* __restrict__ wout,
                                                const float* __restrict__ bout,
                                                float* __restrict__ ws,
                                                float* __restrict__ y) {
    __shared__ __align__(16) char smem[80384];
    unsigned short (*Wl)[136] = (unsigned short(*)[136])smem;
    unsigned short (*Ul)[136] = (unsigned short(*)[136])(smem + 34816);
    unsigned short (*Vl)[136] = (unsigned short(*)[136])(smem + 52224);
    unsigned short (*Mt)[32][40] = (unsigned short(*)[32][40])(smem + 69632);
    float* sD = (float*)(smem + 79872);

    float* pqsum = ws + WS_PQSUM;
    unsigned short* Vst = (unsigned short*)(ws + WS_VST);
    float* pM = ws + WS_PM;

    int bid = blockIdx.x, t = threadIdx.x;
    int b = bid >> 4, nt = bid & 15;
    int lane = t & 63, wave = t >> 6;
    int l15 = lane & 15, lk = (lane >> 4) * 8;
    int wn0 = (wave & 1) * 32;

    if (t < 128) {  // qinv = SCALE_Q / qsum
        float s = 0.f;
        #pragma unroll
        for (int i = 0; i < 16; i++) s += pqsum[((size_t)(b * 16 + i)) * 128 + t];
        sD[t] = SCALE_Q / s;
    }
    {   // stage V tile
        int row = t >> 3, qq = t & 7;
        const uint4* src = (const uint4*)(Vst + ((size_t)bid * 64 + row) * CIN + qq * 16);
        *(uint4*)&Vl[row][qq * 16] = src[0];
        *(uint4*)&Vl[row][qq * 16 + 8] = src[1];
    }
    // reduce pM over the batch's 16 tiles -> Mt[h][c][c'] (transposed, bf16)
    #pragma unroll
    for (int s4 = 0; s4 < 2; s4++) {
        int slot = t + (s4 << 9);          // 0..1023 float4-slots
        int h = slot >> 8, cp = (slot >> 3) & 31, c4 = slot & 7;
        float4 m = { 0.f, 0.f, 0.f, 0.f };
        for (int i = 0; i < 16; i++) {
            const float4 v = *(const float4*)&pM[(((size_t)(b * 16 + i)) * 4 + h) * 1024 + cp * 32 + c4 * 4];
            m.x += v.x; m.y += v.y; m.z += v.z; m.w += v.w;
        }
        Mt[h][c4 * 4 + 0][cp] = f2bf(m.x);
        Mt[h][c4 * 4 + 1][cp] = f2bf(m.y);
        Mt[h][c4 * 4 + 2][cp] = f2bf(m.z);
        Mt[h][c4 * 4 + 3][cp] = f2bf(m.w);
    }
    __syncthreads();

    // u[n][c] = sum_c' v[n][c'] * M[c'][c]  (head = wave>>1, K=32)
    int head = wave >> 1;
    f32x4 uac[2][2] = {};
    {
        bf16x8 mv[2];
        #pragma unroll
        for (int j = 0; j < 2; j++) mv[j] = *(const bf16x8*)&Mt[head][j * 16 + l15][lk];
        #pragma unroll
        for (int i = 0; i < 2; i++) {
            bf16x8 av = *(const bf16x8*)&Vl[wn0 + i * 16 + l15][head * 32 + lk];
            #pragma unroll
            for (int j = 0; j < 2; j++)
                uac[i][j] = __builtin_amdgcn_mfma_f32_16x16x32_bf16(av, mv[j], uac[i][j], 0, 0, 0);
        }
    }
    {   // stage wout scaled by qinv -> Wl bf16 (o = t>>2, qtr = t&3)
        int o = t >> 2, qtr = t & 3;
        const float4* src = (const float4*)(wout + (size_t)o * CIN + qtr * 32);
        unsigned pk[16];
        #pragma unroll
        for (int i = 0; i < 8; i++) {
            float4 v = src[i];
            int c = qtr * 32 + i * 4;
            v.x *= sD[c]; v.y *= sD[c + 1]; v.z *= sD[c + 2]; v.w *= sD[c + 3];
            pk[2 * i] = pack2(v.x, v.y);
            pk[2 * i + 1] = pack2(v.z, v.w);
        }
        uint4* dst = (uint4*)&Wl[o][qtr * 32];
        #pragma unroll
        for (int j = 0; j < 4; j++) dst[j] = *(uint4*)(pk + j * 4);
    }
    // scatter u -> Ul[n][head*32+c]
    #pragma unroll
    for (int i = 0; i < 2; i++)
        #pragma unroll
        for (int j = 0; j < 2; j++) {
            int ch = head * 32 + j * 16 + l15;
            #pragma unroll
            for (int r = 0; r < 4; r++)
                Ul[wn0 + i * 16 + (lane >> 4) * 4 + r][ch] = f2bf(uac[i][j][r]);
        }
    __syncthreads();

    // y = Wl x Ul^T + bias  (wave: o-slice (wave>>1)*32, token half wn0)
    int wo0 = (wave >> 1) * 32;
    f32x4 yacc[2][2] = {};
    #pragma unroll
    for (int ks = 0; ks < 4; ks++) {
        bf16x8 av[2], bv[2];
        #pragma unroll
        for (int i = 0; i < 2; i++) av[i] = *(const bf16x8*)&Wl[wo0 + i * 16 + l15][ks * 32 + lk];
        #pragma unroll
        for (int j = 0; j < 2; j++) bv[j] = *(const bf16x8*)&Ul[wn0 + j * 16 + l15][ks * 32 + lk];
        #pragma unroll
        for (int i = 0; i < 2; i++)
            #pragma unroll
            for (int j = 0; j < 2; j++)
                yacc[i][j] = __builtin_amdgcn_mfma_f32_16x16x32_bf16(av[i], bv[j], yacc[i][j], 0, 0, 0);
    }
    #pragma unroll
    for (int i = 0; i < 2; i++)
        #pragma unroll
        for (int r = 0; r < 4; r++) {
            int o = wo0 + i * 16 + (lane >> 4) * 4 + r;
            float bias = bout[o];
            float* yp = y + ((size_t)b * CIN + o) * NTOK + nt * 64 + wn0;
            #pragma unroll
            for (int j = 0; j < 2; j++) yp[j * 16 + l15] = yacc[i][j][r] + bias;
        }
}

// ---------------------------------------------------------------------------
extern "C" void kernel_launch(void* const* d_in, const int* in_sizes, int n_in,
                              void* d_out, int out_size, void* d_ws, size_t ws_size,
                              hipStream_t stream) {
    const float* x = (const float*)d_in[0];
    const float* gw = (const float*)d_in[1];
    const float* gb = (const float*)d_in[2];
    const float* wqkv = (const float*)d_in[3];
    const float* wout = (const float*)d_in[4];
    const float* bout = (const float*)d_in[5];
    float* y = (float*)d_out;
    float* ws = (float*)d_ws;

    k_pre<<<dim3(256), 256, 0, stream>>>(x, wqkv, ws);
    k_qkvm<<<dim3(256), 512, 0, stream>>>(x, gw, gb, ws);
    k_out<<<dim3(256), 512, 0, stream>>>(wout, bout, ws, y);
}